// Round 3
// baseline (49.877 us; speedup 1.0000x reference)
//
#include <hip/hip_runtime.h>
#include <hip/hip_bf16.h>

#define BLOCK 256
#define WAVES_PER_BLOCK (BLOCK / 64)
#define GRID_P 1024   // projection kernel blocks (4096 waves)
#define GRID_E 1024   // edge kernel blocks

// Phase 1: per-node projection.  proj[n] = (z_n.Wsrc0, z_n.Wsrc1, z_n.Wdst0, z_n.Wdst1)
// where Wsrc = W[0:128,:], Wdst = W[128:256,:]  (W is row-major [256][2]).
// One wave per node: lane l reads Z[n][2l..2l+1] (float2, coalesced 512B/wave),
// applies its 8 resident weights, then a 64-lane butterfly sums the 4 partials.
__global__ void __launch_bounds__(BLOCK) proj_kernel(
    const float* __restrict__ Z,
    const float* __restrict__ W,
    float4*      __restrict__ proj,
    int n_nodes)
{
    const int lane = threadIdx.x & 63;
    const int wid  = threadIdx.x >> 6;
    const int gw   = blockIdx.x * WAVES_PER_BLOCK + wid;
    const int nwaves = gridDim.x * WAVES_PER_BLOCK;

    // This lane covers feature rows k0 = 2*lane and k0+1.
    const int k0 = 2 * lane;
    const float a0 = W[(k0    ) * 2 + 0], a1 = W[(k0    ) * 2 + 1];
    const float b0 = W[(k0 + 1) * 2 + 0], b1 = W[(k0 + 1) * 2 + 1];
    const float c0 = W[(128 + k0    ) * 2 + 0], c1 = W[(128 + k0    ) * 2 + 1];
    const float d0 = W[(128 + k0 + 1) * 2 + 0], d1 = W[(128 + k0 + 1) * 2 + 1];

    for (int n = gw; n < n_nodes; n += nwaves) {
        const float2 z = ((const float2*)(Z + (size_t)n * 128))[lane];

        float t0 = z.x * a0 + z.y * b0;   // src, class 0
        float t1 = z.x * a1 + z.y * b1;   // src, class 1
        float t2 = z.x * c0 + z.y * d0;   // dst, class 0
        float t3 = z.x * c1 + z.y * d1;   // dst, class 1

#pragma unroll
        for (int m = 32; m >= 1; m >>= 1) {
            t0 += __shfl_xor(t0, m, 64);
            t1 += __shfl_xor(t1, m, 64);
            t2 += __shfl_xor(t2, m, 64);
            t3 += __shfl_xor(t3, m, 64);
        }
        if (lane == 0) proj[n] = make_float4(t0, t1, t2, t3);
    }
}

// Phase 2: per-edge loss from the 1.6MB proj table (L2/L3-resident gathers).
__global__ void __launch_bounds__(BLOCK) edge_kernel(
    const float4* __restrict__ proj,
    const int*    __restrict__ edges,
    const int*    __restrict__ y,
    float*        __restrict__ partials,
    int n_edges)
{
    const int tid = blockIdx.x * BLOCK + threadIdx.x;
    const int nthreads = gridDim.x * BLOCK;

    float acc = 0.0f;
    for (int e = tid; e < n_edges; e += nthreads) {
        const int2 ed = ((const int2*)edges)[e];
        const float4 ps = proj[ed.x];
        const float4 pd = proj[ed.y];
        const float s0 = ps.x + pd.z;
        const float s1 = ps.y + pd.w;

        const float mx  = fmaxf(s0, s1);
        const float lse = mx + logf(expf(s0 - mx) + expf(s1 - mx));
        const float sy  = (y[e] != 0) ? s1 : s0;
        acc += lse - sy;   // = -log_softmax(scores)[y]
    }

    __shared__ float sm[BLOCK];
    sm[threadIdx.x] = acc;
    __syncthreads();
    for (int off = BLOCK / 2; off >= 1; off >>= 1) {
        if (threadIdx.x < off) sm[threadIdx.x] += sm[threadIdx.x + off];
        __syncthreads();
    }
    if (threadIdx.x == 0) partials[blockIdx.x] = sm[0];
}

// Phase 3: deterministic final reduction.
__global__ void __launch_bounds__(BLOCK) reduce_kernel(
    const float* __restrict__ partials, int n,
    float* __restrict__ out, float inv_m)
{
    __shared__ float sm[BLOCK];
    float s = 0.0f;
    for (int i = threadIdx.x; i < n; i += BLOCK) s += partials[i];
    sm[threadIdx.x] = s;
    __syncthreads();
    for (int off = BLOCK / 2; off >= 1; off >>= 1) {
        if (threadIdx.x < off) sm[threadIdx.x] += sm[threadIdx.x + off];
        __syncthreads();
    }
    if (threadIdx.x == 0) out[0] = sm[0] * inv_m;
}

extern "C" void kernel_launch(void* const* d_in, const int* in_sizes, int n_in,
                              void* d_out, int out_size, void* d_ws, size_t ws_size,
                              hipStream_t stream)
{
    const float* Z     = (const float*)d_in[0];
    const int*   edges = (const int*)  d_in[1];
    const int*   y     = (const int*)  d_in[2];
    const float* W     = (const float*)d_in[3];
    float* out = (float*)d_out;

    const int n_nodes = in_sizes[0] / 128;
    const int n_edges = in_sizes[1] / 2;

    // Workspace layout: proj table (n_nodes float4), then GRID_E partials.
    float4* proj     = (float4*)d_ws;
    float*  partials = (float*)((char*)d_ws + (size_t)n_nodes * sizeof(float4));

    proj_kernel<<<GRID_P, BLOCK, 0, stream>>>(Z, W, proj, n_nodes);
    edge_kernel<<<GRID_E, BLOCK, 0, stream>>>(proj, edges, y, partials, n_edges);
    reduce_kernel<<<1, BLOCK, 0, stream>>>(partials, GRID_E, out, 1.0f / (float)n_edges);
}